// Round 1
// baseline (1092.527 us; speedup 1.0000x reference)
//
#include <hip/hip_runtime.h>
#include <stdint.h>

#define EPSV 1e-5f

typedef __bf16 bf16x8 __attribute__((ext_vector_type(8)));
typedef float  f32x4  __attribute__((ext_vector_type(4)));

__device__ __forceinline__ unsigned short f2bf(float f) {
    unsigned int u = __builtin_bit_cast(unsigned int, f);
    unsigned int r = (u + 0x7FFFu + ((u >> 16) & 1u)) >> 16;
    return (unsigned short)r;
}
__device__ __forceinline__ float bf2f(unsigned short b) {
    unsigned int u = ((unsigned int)b) << 16;
    return __builtin_bit_cast(float, u);
}

// ---------------------------------------------------------------------------
// Prep 1: W[k][i][0:64] -> bf16 hi/lo (layout [k*64+i][j], j contiguous),
//         bias[k*64+i] = sum_j cm[k][j] * W[k][i][64+j]   (fp32 exact-ish)
// One wave per (k,i) row. grid = 1024 blocks x 256 threads (4 waves/block).
// ---------------------------------------------------------------------------
__global__ __launch_bounds__(256) void wprep_kernel(
    const float* __restrict__ W, const float* __restrict__ cm,
    unsigned short* __restrict__ Whi, unsigned short* __restrict__ Wlo,
    float* __restrict__ bias) {
    int tid  = threadIdx.x;
    int idx  = blockIdx.x * 4 + (tid >> 6);   // 0..4095 == k*64+i
    int j    = tid & 63;
    int k    = idx >> 6;

    float w = W[(size_t)idx * 128 + j];
    unsigned short h = f2bf(w);
    float hf = bf2f(h);
    unsigned short l = f2bf(w - hf);
    Whi[(size_t)idx * 64 + j] = h;
    Wlo[(size_t)idx * 64 + j] = l;

    float b = cm[k * 64 + j] * W[(size_t)idx * 128 + 64 + j];
    b += __shfl_xor(b, 1);
    b += __shfl_xor(b, 2);
    b += __shfl_xor(b, 4);
    b += __shfl_xor(b, 8);
    b += __shfl_xor(b, 16);
    b += __shfl_xor(b, 32);
    if (j == 0) bias[idx] = b;
}

// ---------------------------------------------------------------------------
// Prep 2: x (B=4, C=64, N=16384) -> xt[m][j] bf16 hi/lo, m = b*16384 + n.
// 64x64 LDS tile transpose. grid = (256 n-tiles, 4 b) x 256 threads.
// ---------------------------------------------------------------------------
__global__ __launch_bounds__(256) void xprep_kernel(
    const float* __restrict__ x,
    unsigned short* __restrict__ xhi, unsigned short* __restrict__ xlo) {
    __shared__ float tile[64][65];
    int b   = blockIdx.y;
    int n0  = blockIdx.x * 64;
    int tid = threadIdx.x;

    // read: thread -> (j = tid>>2, column group tid&3 of 16 floats)
    {
        int j  = tid >> 2;
        int cg = tid & 3;
        const float4* src =
            (const float4*)(x + ((size_t)(b * 64 + j)) * 16384 + n0 + cg * 16);
        #pragma unroll
        for (int c = 0; c < 4; ++c) {
            float4 v = src[c];
            int nn = cg * 16 + c * 4;
            tile[j][nn + 0] = v.x;
            tile[j][nn + 1] = v.y;
            tile[j][nn + 2] = v.z;
            tile[j][nn + 3] = v.w;
        }
    }
    __syncthreads();
    // write: thread -> (n_local = tid>>2, j group tid&3 of 16 j's)
    {
        int nl = tid >> 2;
        int jq = tid & 3;
        size_t m = (size_t)b * 16384 + n0 + nl;
        union { unsigned short u16[16]; uint4 u4[2]; } ph, pl;
        #pragma unroll
        for (int jj = 0; jj < 16; ++jj) {
            float v = tile[jq * 16 + jj][nl];
            unsigned short h = f2bf(v);
            ph.u16[jj] = h;
            pl.u16[jj] = f2bf(v - bf2f(h));
        }
        uint4* dh = (uint4*)(xhi + m * 64 + jq * 16);
        uint4* dl = (uint4*)(xlo + m * 64 + jq * 16);
        dh[0] = ph.u4[0]; dh[1] = ph.u4[1];
        dl[0] = pl.u4[0]; dl[1] = pl.u4[1];
    }
}

// ---------------------------------------------------------------------------
// Main: grid (128 m-chunks, 16 k-groups) x 256 threads (4 waves; wave = one k).
// Per wave: B frags for its k persist in VGPRs; loop 32 m-tiles of 16 rows.
// 3-term bf16 hi/lo split MFMA (16x16x32), bias-init accumulators, clip,
// 16-lane butterfly row-sum, rcp-normalize, nontemporal stores.
// ---------------------------------------------------------------------------
__global__ __launch_bounds__(256, 3) void main_kernel(
    const unsigned short* __restrict__ xhi, const unsigned short* __restrict__ xlo,
    const unsigned short* __restrict__ Whi, const unsigned short* __restrict__ Wlo,
    const float* __restrict__ bias, float* __restrict__ out) {
    int kg    = blockIdx.y;            // 0..15
    int chunk = blockIdx.x;            // 0..127
    int wave  = threadIdx.x >> 6;
    int lane  = threadIdx.x & 63;
    int li    = lane & 15;
    int quad  = lane >> 4;
    int k     = kg * 4 + wave;

    // Persistent B fragments: B[j][i] = Wx[k][i][j]; lane holds i=li, j=quad*8+jj
    bf16x8 Bh[4][2], Bl[4][2];
    float  bv[4];
    #pragma unroll
    for (int t = 0; t < 4; ++t) {
        int i = t * 16 + li;
        bv[t] = bias[k * 64 + i];
        #pragma unroll
        for (int h = 0; h < 2; ++h) {
            size_t off = ((size_t)(k * 64 + i)) * 64 + h * 32 + quad * 8;
            Bh[t][h] = __builtin_bit_cast(bf16x8, *(const uint4*)(Whi + off));
            Bl[t][h] = __builtin_bit_cast(bf16x8, *(const uint4*)(Wlo + off));
        }
    }

    #pragma unroll 1
    for (int mt = 0; mt < 32; ++mt) {
        int m0 = (chunk * 32 + mt) * 16;
        size_t arow = ((size_t)(m0 + li)) * 64;
        bf16x8 Ah[2], Al[2];
        #pragma unroll
        for (int h = 0; h < 2; ++h) {
            size_t off = arow + h * 32 + quad * 8;
            Ah[h] = __builtin_bit_cast(bf16x8, *(const uint4*)(xhi + off));
            Al[h] = __builtin_bit_cast(bf16x8, *(const uint4*)(xlo + off));
        }

        f32x4 acc[4];
        #pragma unroll
        for (int t = 0; t < 4; ++t) {
            f32x4 a = {bv[t], bv[t], bv[t], bv[t]};
            #pragma unroll
            for (int h = 0; h < 2; ++h) {
                a = __builtin_amdgcn_mfma_f32_16x16x32_bf16(Ah[h], Bh[t][h], a, 0, 0, 0);
                a = __builtin_amdgcn_mfma_f32_16x16x32_bf16(Al[h], Bh[t][h], a, 0, 0, 0);
                a = __builtin_amdgcn_mfma_f32_16x16x32_bf16(Ah[h], Bl[t][h], a, 0, 0, 0);
            }
            acc[t] = a;
        }

        // clip + per-row (m) sum over i: in-lane over 4 t-tiles, then 16-lane butterfly
        float s[4] = {0.f, 0.f, 0.f, 0.f};
        #pragma unroll
        for (int t = 0; t < 4; ++t)
            #pragma unroll
            for (int r = 0; r < 4; ++r) {
                float v = fminf(fmaxf(acc[t][r], EPSV), 1.0f - EPSV);
                acc[t][r] = v;
                s[r] += v;
            }
        #pragma unroll
        for (int r = 0; r < 4; ++r) {
            s[r] += __shfl_xor(s[r], 1);
            s[r] += __shfl_xor(s[r], 2);
            s[r] += __shfl_xor(s[r], 4);
            s[r] += __shfl_xor(s[r], 8);
            s[r] = __builtin_amdgcn_rcpf(s[r]);
        }

        // out[m][k][i], m = m0 + quad*4 + r, i = t*16 + li
        size_t obase = (size_t)(m0 + quad * 4) * 4096 + (size_t)(k << 6) + li;
        #pragma unroll
        for (int r = 0; r < 4; ++r)
            #pragma unroll
            for (int t = 0; t < 4; ++t)
                __builtin_nontemporal_store(acc[t][r] * s[r],
                                            out + obase + (size_t)r * 4096 + t * 16);
    }
}

// ---------------------------------------------------------------------------
extern "C" void kernel_launch(void* const* d_in, const int* in_sizes, int n_in,
                              void* d_out, int out_size, void* d_ws, size_t ws_size,
                              hipStream_t stream) {
    const float* x  = (const float*)d_in[0];   // (4, 64, 16384)
    const float* cm = (const float*)d_in[1];   // (64, 64)
    const float* W  = (const float*)d_in[2];   // (64, 64, 128)
    float* out = (float*)d_out;                // (65536, 64, 64)

    char* ws = (char*)d_ws;
    // ws layout (bytes): xt_hi 8Mi | xt_lo 8Mi | W_hi 512Ki | W_lo 512Ki | bias 16Ki
    unsigned short* xhi  = (unsigned short*)(ws);
    unsigned short* xlo  = (unsigned short*)(ws + 8388608);
    unsigned short* whi  = (unsigned short*)(ws + 16777216);
    unsigned short* wlo  = (unsigned short*)(ws + 17301504);
    float*          bias = (float*)(ws + 17825792);

    wprep_kernel<<<1024, 256, 0, stream>>>(W, cm, whi, wlo, bias);
    xprep_kernel<<<dim3(256, 4), 256, 0, stream>>>(x, xhi, xlo);
    main_kernel<<<dim3(128, 16), 256, 0, stream>>>(xhi, xlo, whi, wlo, bias, out);
}